// Round 17
// baseline (1031.031 us; speedup 1.0000x reference)
//
#include <hip/hip_runtime.h>
#include <type_traits>

// LSTMNet: B=1024, T=2048, H=64, NC=10, input_size=1.
// MFMA (16x16x32 bf16) single-pass (W,h bf16 — R14-verified, absmax 9.8e-4).
// R17: unit-split waves + IN-WAVE bpermute spread -> ONE barrier/step,
// lane-packed transcendentals.
//   R16 post-mortem: wall = serial chain x 2048 (~1010 cyc/step, pipes <25%
//   busy); ~620 cyc is latency: 2 barriers + 2 LDS round-trips (A, gbuf).
//   Fix: wave w owns units [16w,16w+16) x all 4 gates (8 MFMAs, R15 tiling).
//   C-layout lands cells (r, u=16w+col) in quad-0 lanes; redistribute with
//   ds_bpermute (src lane = col) + quad-select so EVERY lane owns 1 cell ->
//   10 full-rate trans/wave (R15's 4x exec-masked trans avoided), update
//   in-register, h written straight to swizzled abuf. gbuf deleted; one
//   cross-wave exchange (h) -> one barrier.
// Kept verified pieces: single-pass bf16 MFMA, swizzled abuf (2-way), 32KB
// LDS union, x chunking (x via 4-addr broadcast ds_read), t-loop unroll x2.

#define T_STEPS 2048
#define HID 64
#define NCLS 10
#define XCH 128   // x chunk length (steps)
#define ROWS 4    // batch rows per block

typedef short bf16x8 __attribute__((ext_vector_type(8)));
typedef float f32x4 __attribute__((ext_vector_type(4)));

__device__ __forceinline__ float sigm(float x) {
    float e = __builtin_amdgcn_exp2f(-1.4426950408889634f * x);
    return __builtin_amdgcn_rcpf(1.0f + e);
}
__device__ __forceinline__ float tanh_f(float x) {
    float e = __builtin_amdgcn_exp2f(-2.8853900817779268f * x);
    return fmaf(2.0f, __builtin_amdgcn_rcpf(1.0f + e), -1.0f);
}
__device__ __forceinline__ unsigned short f2bf(float f) {  // RNE f32->bf16
    unsigned u = __builtin_bit_cast(unsigned, f);
    u = u + 0x7FFFu + ((u >> 16) & 1u);
    return (unsigned short)(u >> 16);
}
__device__ __forceinline__ float bperm_f(int srclane4, float v) {
    int r = __builtin_amdgcn_ds_bpermute(srclane4, __builtin_bit_cast(int, v));
    return __builtin_bit_cast(float, r);
}

__global__ __attribute__((amdgpu_flat_work_group_size(256, 256),
                          amdgpu_waves_per_eu(1, 1)))
void lstm_mfma_kernel(
    const float* __restrict__ x,      // [B, 1, T]
    const float* __restrict__ W_ih,   // [256, 1]
    const float* __restrict__ W_hh,   // [256, 64]
    const float* __restrict__ b_ih,   // [256]
    const float* __restrict__ b_hh,   // [256]
    const float* __restrict__ fc1_w,  // [64, 64]
    const float* __restrict__ fc1_b,  // [64]
    const float* __restrict__ fc2_w,  // [10, 64]
    const float* __restrict__ fc2_b,  // [10]
    float* __restrict__ out)          // [B, 10]
{
    const int tid  = threadIdx.x;
    const int lane = tid & 63;
    const int w    = tid >> 6;        // wave id = unit-16-block
    const int quad = lane >> 4;
    const int col  = lane & 15;
    const int row0 = blockIdx.x * ROWS;

    // ---- LDS union: 32KB staging (dead after B-frag load) overlaps runtime ----
    __shared__ __align__(16) char smem[32768];
    short* whi = (short*)smem;                 // staging [0,32768)
    // runtime (valid only after the staging->register handoff sync):
    short (*abuf)[1088]        = (short(*)[1088])smem;              // 4352 B
    float (*xlds)[XCH + 4]     = (float(*)[XCH + 4])(smem + 4352);  // 2112 B
    float (*hf)[HID + 1]       = (float(*)[HID + 1])(smem + 6464);  // 1040 B
    float (*r1buf)[HID + 1]    = (float(*)[HID + 1])(smem + 7504);  // 1040 B

    // ---- stage: W_hh f32 -> bf16 fragments (R5-verified layout) ----
    for (int idx = tid; idx < 256 * 64; idx += 256) {
        int r_ = idx >> 6;            // gate-major row 0..255
        int k  = idx & 63;
        float f = W_hh[r_ * 64 + k];
        int g = r_ >> 6, u = r_ & 63;
        int u4 = u >> 4, n = u & 15;
        int kt = k >> 5, kq = (k & 31) >> 3, j = k & 7;
        int off = (((u4 * 4 + g) * 2 + kt) * 64 + (kq * 16 + n)) * 8 + j;
        whi[off] = (short)f2bf(f);
    }
    __syncthreads();

    // ---- B fragments -> registers: wave w = unit block, all 4 gates ----
    bf16x8 Bq[4][2];
    f32x4 biasC[4];
    const int u_c = w * 16 + col;     // unit for C-column `col` of this wave
    #pragma unroll
    for (int g = 0; g < 4; ++g) {
        int t_ = w * 4 + g;
        #pragma unroll
        for (int kt = 0; kt < 2; ++kt) {
            int off = ((t_ * 2 + kt) * 64 + lane) * 8;
            Bq[g][kt] = *(const bf16x8*)&whi[off];
            asm volatile("" : "+v"(Bq[g][kt]));
        }
        float bs = b_ih[g * HID + u_c] + b_hh[g * HID + u_c];
        #pragma unroll
        for (int r = 0; r < 4; ++r) biasC[g][r] = bs;
    }
    __syncthreads();   // all waves done READING staging; smem may be reused now

    // zero BOTH A buffers (rows 4..15 never written -> stay zero = h0)
    for (int idx = tid; idx < 2 * 1088; idx += 256) ((short*)abuf)[idx] = 0;

    // ---- update constants: this lane owns cell (row m = quad, unit u_c) ----
    float wih_u[4];
    #pragma unroll
    for (int g = 0; g < 4; ++g) wih_u[g] = W_ih[g * HID + u_c];
    float cc = 0.f, hl = 0.f;

    // invariant LDS coords
    const int ard0 = lane * 8 + (lane >> 4) * 8;   // A-read (kt=1 at +544)
    // h-write swizzled slot for (m=quad, k=u_c):
    const int s_w = (u_c >> 5) * 4 + ((u_c >> 3) & 3);
    const int awr = (s_w * 16 + quad) * 8 + s_w * 8 + (u_c & 7);
    const int srcl4 = col * 4;                     // bpermute source = lane col

    const float* xbase = x + (size_t)row0 * T_STEPS;
    __syncthreads();   // abuf zeroed

    auto step = [&](auto cur_c, int tl) __attribute__((always_inline)) {
        constexpr int CUR = decltype(cur_c)::value;
        constexpr int NXT = CUR ^ 1;

        // ---- compute: all 4 gates for units [16w,16w+16), 8 MFMAs ----
        bf16x8 Ahi0 = *(const bf16x8*)&abuf[CUR][ard0];
        bf16x8 Ahi1 = *(const bf16x8*)&abuf[CUR][ard0 + 544];

        f32x4 acc[4];
        #pragma unroll
        for (int g = 0; g < 4; ++g) {
            acc[g] = __builtin_amdgcn_mfma_f32_16x16x32_bf16(Ahi0, Bq[g][0], biasC[g], 0, 0, 0);
        }
        #pragma unroll
        for (int g = 0; g < 4; ++g) {
            acc[g] = __builtin_amdgcn_mfma_f32_16x16x32_bf16(Ahi1, Bq[g][1], acc[g], 0, 0, 0);
        }

        // ---- in-wave spread: cell (r, u=16w+col) -> lane r*16+col ----
        // D[r][col] sits in quad-0 lane `col`, reg r. bpermute from lane col,
        // then select reg by this lane's quad. Bit-exact transport.
        float ag[4];
        #pragma unroll
        for (int g = 0; g < 4; ++g) {
            float b0 = bperm_f(srcl4, acc[g][0]);
            float b1 = bperm_f(srcl4, acc[g][1]);
            float b2 = bperm_f(srcl4, acc[g][2]);
            float b3 = bperm_f(srcl4, acc[g][3]);
            float s01 = (quad & 1) ? b1 : b0;
            float s23 = (quad & 1) ? b3 : b2;
            ag[g] = (quad & 2) ? s23 : s01;
        }

        // ---- update: 1 cell/lane (row quad, unit u_c), full-rate trans ----
        float xv = xlds[quad][tl];     // 4-addr broadcast, conflict-free

        float a0 = fmaf(xv, wih_u[0], ag[0]);
        float a1 = fmaf(xv, wih_u[1], ag[1]);
        float a2 = fmaf(xv, wih_u[2], ag[2]);
        float a3 = fmaf(xv, wih_u[3], ag[3]);
        float ig = sigm(a0);
        float fg = sigm(a1);
        float gg = tanh_f(a2);
        float og = sigm(a3);
        cc = fmaf(fg, cc, ig * gg);
        float h = og * tanh_f(cc);
        hl = h;

        abuf[NXT][awr] = (short)f2bf(h);

        __syncthreads();   // new h-frags visible (the ONE barrier)
    };

    #pragma unroll 1
    for (int tc = 0; tc < T_STEPS; tc += 2) {
        const int tl = tc & (XCH - 1);
        if (tl == 0) {
            // refill x chunk (prev step barrier => old chunk fully consumed)
            if (tid < 16 * ROWS) {
                int xr = tid >> 4, tb = (tid & 15) * 8;
                const float* src = xbase + (size_t)xr * T_STEPS + tc + tb;
                float4 v0 = *(const float4*)(src);
                float4 v1 = *(const float4*)(src + 4);
                *(float4*)&xlds[xr][tb]     = v0;
                *(float4*)&xlds[xr][tb + 4] = v1;
            }
            __syncthreads();
        }
        step(std::integral_constant<int, 0>{}, tl);      // reads abuf[0], writes abuf[1]
        step(std::integral_constant<int, 1>{}, tl + 1);  // reads abuf[1], writes abuf[0]
    }

    // ---- epilogue: fc1 (relu) + fc2 ----
    hf[quad][u_c] = hl;   // cell (row quad, unit u_c); 256 distinct slots
    __syncthreads();

    {
        // thread -> (row = w, unit = lane)
        float s = fc1_b[lane];
        const float4* wrow = (const float4*)(fc1_w + lane * HID);
        #pragma unroll
        for (int j4 = 0; j4 < HID / 4; ++j4) {
            float4 wv = wrow[j4];
            s = fmaf(hf[w][j4 * 4 + 0], wv.x, s);
            s = fmaf(hf[w][j4 * 4 + 1], wv.y, s);
            s = fmaf(hf[w][j4 * 4 + 2], wv.z, s);
            s = fmaf(hf[w][j4 * 4 + 3], wv.w, s);
        }
        r1buf[w][lane] = fmaxf(s, 0.0f);
    }
    __syncthreads();

    if (tid < ROWS * NCLS) {
        int m = tid / NCLS, cls = tid % NCLS;
        float s = fc2_b[cls];
        const float* w2 = fc2_w + cls * HID;
        #pragma unroll
        for (int j = 0; j < HID; ++j) s = fmaf(r1buf[m][j], w2[j], s);
        out[(size_t)(row0 + m) * NCLS + cls] = s;
    }
}

extern "C" void kernel_launch(void* const* d_in, const int* in_sizes, int n_in,
                              void* d_out, int out_size, void* d_ws, size_t ws_size,
                              hipStream_t stream) {
    const float* x     = (const float*)d_in[0];
    const float* W_ih  = (const float*)d_in[1];
    const float* W_hh  = (const float*)d_in[2];
    const float* b_ih  = (const float*)d_in[3];
    const float* b_hh  = (const float*)d_in[4];
    const float* fc1_w = (const float*)d_in[5];
    const float* fc1_b = (const float*)d_in[6];
    const float* fc2_w = (const float*)d_in[7];
    const float* fc2_b = (const float*)d_in[8];
    float* out = (float*)d_out;

    dim3 grid(256);   // 1024 rows / 4 rows per block -> 1 block per CU
    dim3 block(256);  // 4 waves
    lstm_mfma_kernel<<<grid, block, 0, stream>>>(x, W_ih, W_hh, b_ih, b_hh,
                                                 fc1_w, fc1_b, fc2_w, fc2_b, out);
}